// Round 2
// baseline (170.289 us; speedup 1.0000x reference)
//
#include <hip/hip_runtime.h>
#include <hip/hip_bf16.h>

#define BATCH 16
#define CDIM 256
#define NDIM 2048
#define HDIM 128
#define KVB 128
#define NT (NDIM / KVB)

typedef __bf16 bf16;
typedef float f32x4 __attribute__((ext_vector_type(4)));
typedef float f32x16 __attribute__((ext_vector_type(16)));
typedef bf16 bf16x8 __attribute__((ext_vector_type(8)));
typedef unsigned int u32x4 __attribute__((ext_vector_type(4)));

#define LOG2E 1.4426950408889634f

// Swizzled byte offsets for row-major bf16 LDS tiles (k1/k3 use these).
__device__ __forceinline__ int swz512(int row, int colbyte) {
  return row * 512 + (colbyte ^ ((row & 15) << 4));
}
__device__ __forceinline__ int swz256(int row, int colbyte) {
  return row * 256 + (colbyte ^ ((row & 7) << 4));
}

__device__ __forceinline__ f32x4 mfma16(bf16x8 a, bf16x8 b, f32x4 c) {
  return __builtin_amdgcn_mfma_f32_16x16x32_bf16(a, b, c, 0, 0, 0);
}
__device__ __forceinline__ f32x16 mfma32(bf16x8 a, bf16x8 b, f32x16 c) {
  return __builtin_amdgcn_mfma_f32_32x32x16_bf16(a, b, c, 0, 0, 0);
}

__device__ __forceinline__ unsigned cvtpk(float lo, float hi) {
  unsigned r;
  asm("v_cvt_pk_bf16_f32 %0, %1, %2" : "=v"(r) : "v"(lo), "v"(hi));
  return r;
}
// After: a = {a.lo32lanes, b.lo32lanes}, b = {a.hi32lanes, b.hi32lanes}
__device__ __forceinline__ void pswap(unsigned &a, unsigned &b) {
  asm volatile("v_permlane32_swap_b32 %0, %1" : "+v"(a), "+v"(b));
}

__device__ __forceinline__ bf16x8 cvt8(float4 a, float4 b) {
  bf16x8 o;
  o[0] = (bf16)a.x; o[1] = (bf16)a.y; o[2] = (bf16)a.z; o[3] = (bf16)a.w;
  o[4] = (bf16)b.x; o[5] = (bf16)b.y; o[6] = (bf16)b.z; o[7] = (bf16)b.w;
  return o;
}

// ---------------------------------------------------------------------------
// Kernel 1: fused QKV projection (unchanged; HBM-bound at roofline).
// ---------------------------------------------------------------------------
__global__ __launch_bounds__(256) void k1_qkv(
    const float* __restrict__ x,
    const float* __restrict__ Wq, const float* __restrict__ bq,
    const float* __restrict__ Wk, const float* __restrict__ bk,
    const float* __restrict__ Wv, const float* __restrict__ bv,
    bf16* __restrict__ Qo, bf16* __restrict__ Ko, bf16* __restrict__ Vo) {
  __shared__ char lds[65536];
  char* xT = lds;            // [64 n][256 c] bf16, 512B rows, swz512 (32 KB)
  char* Wt = lds + 32768;    // [128 h][128 c-half] bf16, swz256 (32 KB)

  const int t = threadIdx.x;
  const int l = t & 63;
  const int w = t >> 6;
  const int b = blockIdx.x >> 5;
  const int n0 = (blockIdx.x & 31) * 64;

#pragma unroll
  for (int pass = 0; pass < 16; ++pass) {
    int c = pass * 16 + (t >> 4);
    int nq = t & 15;
    const float4 v = *reinterpret_cast<const float4*>(
        x + (size_t)(b * CDIM + c) * NDIM + n0 + nq * 4);
    float fv[4] = {v.x, v.y, v.z, v.w};
#pragma unroll
    for (int i = 0; i < 4; ++i) {
      int row = nq * 4 + i;
      *reinterpret_cast<bf16*>(xT + swz512(row, c * 2)) = (bf16)fv[i];
    }
  }

  const float* Wp[3] = {Wq, Wk, Wv};
  const float* bp[3] = {bq, bk, bv};

#pragma unroll 1
  for (int p = 0; p < 3; ++p) {
    f32x4 acc[8];
#pragma unroll
    for (int i = 0; i < 8; ++i) acc[i] = f32x4{0.f, 0.f, 0.f, 0.f};

#pragma unroll 1
    for (int kh = 0; kh < 2; ++kh) {
      __syncthreads();
#pragma unroll
      for (int pass = 0; pass < 8; ++pass) {
        int h = pass * 16 + (t >> 4);
        int cq = t & 15;
        const float* src = Wp[p] + (size_t)h * CDIM + kh * 128 + cq * 8;
        float4 v0 = *reinterpret_cast<const float4*>(src);
        float4 v1 = *reinterpret_cast<const float4*>(src + 4);
        *reinterpret_cast<bf16x8*>(Wt + swz256(h, cq * 16)) = cvt8(v0, v1);
      }
      __syncthreads();

      if (p < 2) {
#pragma unroll
        for (int ks = 0; ks < 4; ++ks) {
          int cb2 = ks * 64 + (l >> 4) * 16;
          bf16x8 a = *reinterpret_cast<const bf16x8*>(
              xT + swz512(w * 16 + (l & 15), kh * 256 + cb2));
#pragma unroll
          for (int nf = 0; nf < 8; ++nf) {
            bf16x8 bb = *reinterpret_cast<const bf16x8*>(
                Wt + swz256(nf * 16 + (l & 15), cb2));
            acc[nf] = mfma16(a, bb, acc[nf]);
          }
        }
      } else {
#pragma unroll
        for (int ks = 0; ks < 4; ++ks) {
          int cb2 = ks * 64 + (l >> 4) * 16;
          bf16x8 a0 = *reinterpret_cast<const bf16x8*>(
              Wt + swz256(w * 32 + (l & 15), cb2));
          bf16x8 a1 = *reinterpret_cast<const bf16x8*>(
              Wt + swz256(w * 32 + 16 + (l & 15), cb2));
#pragma unroll
          for (int nf = 0; nf < 4; ++nf) {
            bf16x8 bb = *reinterpret_cast<const bf16x8*>(
                xT + swz512(nf * 16 + (l & 15), kh * 256 + cb2));
            acc[nf] = mfma16(a0, bb, acc[nf]);
            acc[4 + nf] = mfma16(a1, bb, acc[4 + nf]);
          }
        }
      }
    }

    if (p < 2) {
      bf16* dst = (p == 0) ? Qo : Ko;
#pragma unroll
      for (int nf = 0; nf < 8; ++nf) {
        float bias = bp[p][nf * 16 + (l & 15)];
#pragma unroll
        for (int r = 0; r < 4; ++r) {
          int n = n0 + w * 16 + (l >> 4) * 4 + r;
          int h = nf * 16 + (l & 15);
          dst[(size_t)(b * NDIM + n) * HDIM + h] = (bf16)(acc[nf][r] + bias);
        }
      }
    } else {
#pragma unroll
      for (int mf = 0; mf < 2; ++mf)
#pragma unroll
        for (int nf = 0; nf < 4; ++nf)
#pragma unroll
          for (int r = 0; r < 4; ++r) {
            int h = w * 32 + mf * 16 + (l >> 4) * 4 + r;
            int n = n0 + nf * 16 + (l & 15);
            Vo[(size_t)(b * HDIM + h) * NDIM + n] =
                (bf16)(acc[mf * 4 + nf][r] + bp[2][h]);
          }
    }
  }
}

// ---------------------------------------------------------------------------
// Kernel 2: flash attention, 32x32 MFMA, swapped QK^T, in-register P,
// split-k across wave pairs, double-buffered LDS, 1 barrier per k-tile.
// grid 256 (XCD-swizzled), 512 threads = 8 waves = 4 q-subtiles x 2 k-halves.
// ---------------------------------------------------------------------------
__global__ __launch_bounds__(512, 2) void k2_attn(
    const bf16* __restrict__ Q, const bf16* __restrict__ K,
    const bf16* __restrict__ V, bf16* __restrict__ O) {
  extern __shared__ char lds[];
  // buf0 @0, buf1 @65536; each: Kt [128 kpos][256B] @0, Vt [128 d][256B] @32768
  char* FACB = lds + 131072;                 // 8 waves * 256B
  float* M1 = (float*)(lds + 133120);        // [4][64]
  float* L1 = (float*)(lds + 134144);
  float* G0 = (float*)(lds + 135168);
  float* G1 = (float*)(lds + 136192);

  const int t = threadIdx.x;
  const int l = t & 63;
  const int w = t >> 6;     // 0..7
  const int wm = w >> 1;    // q-subtile 0..3 (32 rows each)
  const int wk = w & 1;     // kpos half 0..1
  const int hi = l >> 5;
  const int c31 = l & 31;

  const int pid = blockIdx.x;
  const int b = (pid & 7) * 2 + ((pid >> 3) >> 4);
  const int q0 = ((pid >> 3) & 15) * 128;

  // Q fragments, B-operand layout: lane holds Q[q0+wm*32+c31][cs*16+hi*8+j]
  bf16x8 qf[8];
  {
    const bf16* qrow = Q + (size_t)(b * NDIM + q0 + wm * 32 + c31) * HDIM + hi * 8;
#pragma unroll
    for (int cs = 0; cs < 8; ++cs)
      qf[cs] = *reinterpret_cast<const bf16x8*>(qrow + cs * 16);
  }

  // Staging: waves 0-3 stage Kt rows w*32.., waves 4-7 stage Vt rows (w-4)*32..
  // LDS linear slots; XOR-swizzle applied on the global SOURCE address so that
  // content(slot) = source col-slot (slot ^ (row&15))  [rule #21 both-sides].
  const bool isV = (w >= 4);
  const int rbase = (isV ? (w - 4) : w) * 32 + (l >> 4);
  const int slot = l & 15;
  const bf16* gsrc[8];
#pragma unroll
  for (int i = 0; i < 8; ++i) {
    int r = rbase + i * 4;
    int soff = ((slot ^ (r & 15)) * 8);
    gsrc[i] = isV ? (V + (size_t)(b * HDIM + r) * NDIM + soff)
                  : (K + (size_t)(b * NDIM + r) * HDIM + soff);
  }
  const size_t gstep = isV ? (size_t)KVB : (size_t)KVB * HDIM;
  const int ldsoff = (isV ? 32768 : 0) + rbase * 256 + slot * 16;

  // prologue: tile 0 in flight
  uint4 g[8];
#pragma unroll
  for (int i = 0; i < 8; ++i) g[i] = *reinterpret_cast<const uint4*>(gsrc[i]);

  f32x16 oacc[4];
#pragma unroll
  for (int dg = 0; dg < 4; ++dg)
#pragma unroll
    for (int r = 0; r < 16; ++r) oacc[dg][r] = 0.f;
  float m_run = -3.0e38f, l_run = 0.f;

#pragma unroll 1
  for (int kt = 0; kt < NT; ++kt) {
    char* buf = lds + (kt & 1) * 65536;
    // stage tile kt (compiler inserts vmcnt waits on g[])
#pragma unroll
    for (int i = 0; i < 8; ++i)
      *reinterpret_cast<uint4*>(buf + ldsoff + i * 1024) = g[i];
    // issue tile kt+1
    if (kt + 1 < NT) {
#pragma unroll
      for (int i = 0; i < 8; ++i)
        g[i] = *reinterpret_cast<const uint4*>(gsrc[i] + (size_t)(kt + 1) * gstep);
    }
    asm volatile("s_waitcnt lgkmcnt(0)" ::: "memory");
    __builtin_amdgcn_s_barrier();

    const char* Kt = buf;
    const char* Vt = buf + 32768;

    // S^T = mfma(K, Q): D[kpos_local][q], lane = q (col), kpos in regs.
    f32x16 s[2];
#pragma unroll
    for (int kg = 0; kg < 2; ++kg)
#pragma unroll
      for (int r = 0; r < 16; ++r) s[kg][r] = 0.f;
#pragma unroll
    for (int kg = 0; kg < 2; ++kg) {
      int row = wk * 64 + kg * 32 + c31;
      const char* kr = Kt + row * 256;
      int rx = row & 15;
#pragma unroll
      for (int cs = 0; cs < 8; ++cs) {
        bf16x8 kf = *reinterpret_cast<const bf16x8*>(kr + (((cs * 2 + hi) ^ rx) * 16));
        s[kg] = mfma32(kf, qf[cs], s[kg]);
      }
    }

    // Online softmax: all stats lane-local (lane = q), hi/lo combine via xor32.
    float mt = s[0][0];
#pragma unroll
    for (int r = 1; r < 16; ++r) mt = fmaxf(mt, s[0][r]);
#pragma unroll
    for (int r = 0; r < 16; ++r) mt = fmaxf(mt, s[1][r]);
    mt = fmaxf(mt, __shfl_xor(mt, 32));
    float mnew = fmaxf(m_run, mt);
    float fac = exp2f((m_run - mnew) * LOG2E);
    m_run = mnew;
    float sum = 0.f;
#pragma unroll
    for (int kg = 0; kg < 2; ++kg)
#pragma unroll
      for (int r = 0; r < 16; ++r) {
        float p = exp2f((s[kg][r] - mnew) * LOG2E);
        s[kg][r] = p;
        sum += p;
      }
    sum += __shfl_xor(sum, 32);
    l_run = l_run * fac + sum;

    // Broadcast fac (indexed by q) to the per-reg q' positions of O-frags.
    *reinterpret_cast<float*>(FACB + w * 256 + l * 4) = fac;
    asm volatile("s_waitcnt lgkmcnt(0)" ::: "memory");
    f32x4 fv[4];
#pragma unroll
    for (int gi = 0; gi < 4; ++gi)
      fv[gi] = *reinterpret_cast<const f32x4*>(
          FACB + w * 256 + hi * 128 + (gi * 8 + hi * 4) * 4);
#pragma unroll
    for (int dg = 0; dg < 4; ++dg)
#pragma unroll
      for (int r = 0; r < 16; ++r) oacc[dg][r] *= fv[r >> 2][r & 3];

    // P -> bf16 A-fragments in-register (cvt_pk + permlane32_swap), then PV.
#pragma unroll
    for (int kg = 0; kg < 2; ++kg) {
      unsigned w0 = cvtpk(s[kg][0], s[kg][1]);
      unsigned w1 = cvtpk(s[kg][2], s[kg][3]);
      unsigned w2 = cvtpk(s[kg][4], s[kg][5]);
      unsigned w3 = cvtpk(s[kg][6], s[kg][7]);
      unsigned w4 = cvtpk(s[kg][8], s[kg][9]);
      unsigned w5 = cvtpk(s[kg][10], s[kg][11]);
      unsigned w6 = cvtpk(s[kg][12], s[kg][13]);
      unsigned w7 = cvtpk(s[kg][14], s[kg][15]);
      pswap(w0, w2); pswap(w1, w3); pswap(w4, w6); pswap(w5, w7);
      u32x4 pw0 = {w0, w1, w2, w3};
      u32x4 pw1 = {w4, w5, w6, w7};
      bf16x8 pa0 = __builtin_bit_cast(bf16x8, pw0);
      bf16x8 pa1 = __builtin_bit_cast(bf16x8, pw1);
#pragma unroll
      for (int dg = 0; dg < 4; ++dg) {
        int vrow = dg * 32 + c31;
        const char* vr = Vt + vrow * 256;
        int vx = vrow & 15;
        bf16x8 vf0 = *reinterpret_cast<const bf16x8*>(
            vr + (((wk * 8 + kg * 4 + 0 + hi) ^ vx) * 16));
        oacc[dg] = mfma32(pa0, vf0, oacc[dg]);
        bf16x8 vf1 = *reinterpret_cast<const bf16x8*>(
            vr + (((wk * 8 + kg * 4 + 2 + hi) ^ vx) * 16));
        oacc[dg] = mfma32(pa1, vf1, oacc[dg]);
      }
    }
  }

  // ---- split-k merge across (wk=0, wk=1) wave pairs; buf0 free for O1.
  if (wk == 1) {
#pragma unroll
    for (int dg = 0; dg < 4; ++dg)
#pragma unroll
      for (int r = 0; r < 16; ++r)
        ((float*)lds)[(((wm * 4 + dg) * 16 + r) << 6) + l] = oacc[dg][r];
    M1[wm * 64 + l] = m_run;
    L1[wm * 64 + l] = l_run;
  }
  asm volatile("s_waitcnt lgkmcnt(0)" ::: "memory");
  __builtin_amdgcn_s_barrier();
  if (wk == 0) {
    float m1 = M1[wm * 64 + l];
    float l1v = L1[wm * 64 + l];
    float mf = fmaxf(m_run, m1);
    float a0 = exp2f((m_run - mf) * LOG2E);
    float a1 = exp2f((m1 - mf) * LOG2E);
    float lf = l_run * a0 + l1v * a1;
    G0[wm * 64 + l] = a0 / lf;
    G1[wm * 64 + l] = a1 / lf;
    asm volatile("s_waitcnt lgkmcnt(0)" ::: "memory");
    f32x4 g0v[4], g1v[4];
#pragma unroll
    for (int gi = 0; gi < 4; ++gi) {
      int qi = wm * 64 + hi * 32 + gi * 8 + hi * 4;
      g0v[gi] = *reinterpret_cast<const f32x4*>(&G0[qi]);
      g1v[gi] = *reinterpret_cast<const f32x4*>(&G1[qi]);
    }
#pragma unroll
    for (int dg = 0; dg < 4; ++dg) {
      int h = dg * 32 + c31;
#pragma unroll
      for (int r = 0; r < 16; ++r) {
        float o1 = ((float*)lds)[(((wm * 4 + dg) * 16 + r) << 6) + l];
        float val = oacc[dg][r] * g0v[r >> 2][r & 3] + o1 * g1v[r >> 2][r & 3];
        int n = q0 + wm * 32 + (r & 3) + 8 * (r >> 2) + 4 * hi;
        O[(size_t)(b * NDIM + n) * HDIM + h] = (bf16)val;
      }
    }
  }
}

// ---------------------------------------------------------------------------
// Kernel 3: out = Wf @ O + bf + x (unchanged; HBM-bound at roofline)
// ---------------------------------------------------------------------------
__global__ __launch_bounds__(256) void k3_proj(
    const bf16* __restrict__ O, const float* __restrict__ Wf,
    const float* __restrict__ bfv, const float* __restrict__ x,
    float* __restrict__ out) {
  __shared__ char lds[49152];
  char* Wt = lds;
  char* Ot = lds + 32768;

  const int t = threadIdx.x;
  const int l = t & 63;
  const int w = t >> 6;
  const int b = blockIdx.x >> 5;
  const int n0 = (blockIdx.x & 31) * 64;

#pragma unroll
  for (int pass = 0; pass < 4; ++pass) {
    int n = pass * 16 + (t >> 4);
    int hq = t & 15;
    uint4 d = *reinterpret_cast<const uint4*>(
        O + (size_t)(b * NDIM + n0 + n) * HDIM + hq * 8);
    *reinterpret_cast<uint4*>(Ot + swz256(n, hq * 16)) = d;
  }

#pragma unroll 1
  for (int ch = 0; ch < 2; ++ch) {
    __syncthreads();
#pragma unroll
    for (int pass = 0; pass < 8; ++pass) {
      int cl = pass * 16 + (t >> 4);
      int hq = t & 15;
      const float* src = Wf + (size_t)(ch * 128 + cl) * HDIM + hq * 8;
      float4 v0 = *reinterpret_cast<const float4*>(src);
      float4 v1 = *reinterpret_cast<const float4*>(src + 4);
      *reinterpret_cast<bf16x8*>(Wt + swz256(cl, hq * 16)) = cvt8(v0, v1);
    }
    __syncthreads();

    f32x4 acc[2][4];
#pragma unroll
    for (int i = 0; i < 2; ++i)
#pragma unroll
      for (int j = 0; j < 4; ++j) acc[i][j] = f32x4{0.f, 0.f, 0.f, 0.f};

#pragma unroll
    for (int ks = 0; ks < 4; ++ks) {
      int cb = ks * 64 + (l >> 4) * 16;
      bf16x8 a0 = *reinterpret_cast<const bf16x8*>(
          Wt + swz256(w * 32 + (l & 15), cb));
      bf16x8 a1 = *reinterpret_cast<const bf16x8*>(
          Wt + swz256(w * 32 + 16 + (l & 15), cb));
#pragma unroll
      for (int nf = 0; nf < 4; ++nf) {
        bf16x8 bb = *reinterpret_cast<const bf16x8*>(
            Ot + swz256(nf * 16 + (l & 15), cb));
        acc[0][nf] = mfma16(a0, bb, acc[0][nf]);
        acc[1][nf] = mfma16(a1, bb, acc[1][nf]);
      }
    }

#pragma unroll
    for (int mf = 0; mf < 2; ++mf)
#pragma unroll
      for (int nf = 0; nf < 4; ++nf)
#pragma unroll
        for (int r = 0; r < 4; ++r) {
          int c = ch * 128 + w * 32 + mf * 16 + (l >> 4) * 4 + r;
          int n = n0 + nf * 16 + (l & 15);
          size_t idx = (size_t)(b * CDIM + c) * NDIM + n;
          out[idx] = acc[mf][nf][r] + bfv[c] + x[idx];
        }
  }
}

extern "C" void kernel_launch(void* const* d_in, const int* in_sizes, int n_in,
                              void* d_out, int out_size, void* d_ws,
                              size_t ws_size, hipStream_t stream) {
  (void)in_sizes; (void)n_in; (void)out_size;
  const float* x = (const float*)d_in[0];
  const float* Wq = (const float*)d_in[1];
  const float* bq = (const float*)d_in[2];
  const float* Wk = (const float*)d_in[3];
  const float* bk = (const float*)d_in[4];
  const float* Wv = (const float*)d_in[5];
  const float* bv = (const float*)d_in[6];
  const float* Wf = (const float*)d_in[7];
  const float* bfv = (const float*)d_in[8];
  float* out = (float*)d_out;

  if (ws_size < (24u << 20)) return;
  char* ws = (char*)d_ws;
  bf16* Qb = (bf16*)(ws);                  // 8 MB [B][N][H]; reused as O
  bf16* Kb = (bf16*)(ws + (8u << 20));     // 8 MB [B][N][H]
  bf16* Vb = (bf16*)(ws + (16u << 20));    // 8 MB [B][H][N]

  const unsigned k2_lds = 137216;  // 2x64KB dbuf + fac/merge scratch
  hipFuncSetAttribute(reinterpret_cast<const void*>(k2_attn),
                      hipFuncAttributeMaxDynamicSharedMemorySize, (int)k2_lds);

  k1_qkv<<<512, 256, 0, stream>>>(x, Wq, bq, Wk, bk, Wv, bv, Qb, Kb, Vb);
  k2_attn<<<256, 512, k2_lds, stream>>>(Qb, Kb, Vb, Qb);
  k3_proj<<<512, 256, 0, stream>>>(Qb, Wf, bfv, x, out);
}

// Round 3
// 94.988 us; speedup vs baseline: 1.7927x; 1.7927x over previous
//
#include <hip/hip_runtime.h>
#include <hip/hip_bf16.h>

#define BATCH 16
#define CDIM 256
#define NDIM 2048
#define HDIM 128
#define KVB 128
#define NT (NDIM / KVB)

typedef __bf16 bf16;
typedef float f32x4 __attribute__((ext_vector_type(4)));
typedef float f32x16 __attribute__((ext_vector_type(16)));
typedef bf16 bf16x8 __attribute__((ext_vector_type(8)));
typedef unsigned int u32x4 __attribute__((ext_vector_type(4)));

#define LOG2E 1.4426950408889634f

// Swizzled byte offsets for row-major bf16 LDS tiles (k1/k3 use these).
__device__ __forceinline__ int swz512(int row, int colbyte) {
  return row * 512 + (colbyte ^ ((row & 15) << 4));
}
__device__ __forceinline__ int swz256(int row, int colbyte) {
  return row * 256 + (colbyte ^ ((row & 7) << 4));
}

__device__ __forceinline__ f32x4 mfma16(bf16x8 a, bf16x8 b, f32x4 c) {
  return __builtin_amdgcn_mfma_f32_16x16x32_bf16(a, b, c, 0, 0, 0);
}
__device__ __forceinline__ f32x16 mfma32(bf16x8 a, bf16x8 b, f32x16 c) {
  return __builtin_amdgcn_mfma_f32_32x32x16_bf16(a, b, c, 0, 0, 0);
}

__device__ __forceinline__ unsigned cvtpk(float lo, float hi) {
  unsigned r;
  asm("v_cvt_pk_bf16_f32 %0, %1, %2" : "=v"(r) : "v"(lo), "v"(hi));
  return r;
}
// After: a = {a.lo32lanes, b.lo32lanes}, b = {a.hi32lanes, b.hi32lanes}
__device__ __forceinline__ void pswap(unsigned &a, unsigned &b) {
  asm volatile("v_permlane32_swap_b32 %0, %1" : "+v"(a), "+v"(b));
}

__device__ __forceinline__ void gload16(const bf16* g, char* l) {
  __builtin_amdgcn_global_load_lds(
      (const __attribute__((address_space(1))) void*)g,
      (__attribute__((address_space(3))) void*)l, 16, 0, 0);
}

__device__ __forceinline__ bf16x8 cvt8(float4 a, float4 b) {
  bf16x8 o;
  o[0] = (bf16)a.x; o[1] = (bf16)a.y; o[2] = (bf16)a.z; o[3] = (bf16)a.w;
  o[4] = (bf16)b.x; o[5] = (bf16)b.y; o[6] = (bf16)b.z; o[7] = (bf16)b.w;
  return o;
}

// ---------------------------------------------------------------------------
// Kernel 1: fused QKV projection (unchanged; near HBM roofline).
// ---------------------------------------------------------------------------
__global__ __launch_bounds__(256) void k1_qkv(
    const float* __restrict__ x,
    const float* __restrict__ Wq, const float* __restrict__ bq,
    const float* __restrict__ Wk, const float* __restrict__ bk,
    const float* __restrict__ Wv, const float* __restrict__ bv,
    bf16* __restrict__ Qo, bf16* __restrict__ Ko, bf16* __restrict__ Vo) {
  __shared__ char lds[65536];
  char* xT = lds;
  char* Wt = lds + 32768;

  const int t = threadIdx.x;
  const int l = t & 63;
  const int w = t >> 6;
  const int b = blockIdx.x >> 5;
  const int n0 = (blockIdx.x & 31) * 64;

#pragma unroll
  for (int pass = 0; pass < 16; ++pass) {
    int c = pass * 16 + (t >> 4);
    int nq = t & 15;
    const float4 v = *reinterpret_cast<const float4*>(
        x + (size_t)(b * CDIM + c) * NDIM + n0 + nq * 4);
    float fv[4] = {v.x, v.y, v.z, v.w};
#pragma unroll
    for (int i = 0; i < 4; ++i) {
      int row = nq * 4 + i;
      *reinterpret_cast<bf16*>(xT + swz512(row, c * 2)) = (bf16)fv[i];
    }
  }

  const float* Wp[3] = {Wq, Wk, Wv};
  const float* bp[3] = {bq, bk, bv};

#pragma unroll 1
  for (int p = 0; p < 3; ++p) {
    f32x4 acc[8];
#pragma unroll
    for (int i = 0; i < 8; ++i) acc[i] = f32x4{0.f, 0.f, 0.f, 0.f};

#pragma unroll 1
    for (int kh = 0; kh < 2; ++kh) {
      __syncthreads();
#pragma unroll
      for (int pass = 0; pass < 8; ++pass) {
        int h = pass * 16 + (t >> 4);
        int cq = t & 15;
        const float* src = Wp[p] + (size_t)h * CDIM + kh * 128 + cq * 8;
        float4 v0 = *reinterpret_cast<const float4*>(src);
        float4 v1 = *reinterpret_cast<const float4*>(src + 4);
        *reinterpret_cast<bf16x8*>(Wt + swz256(h, cq * 16)) = cvt8(v0, v1);
      }
      __syncthreads();

      if (p < 2) {
#pragma unroll
        for (int ks = 0; ks < 4; ++ks) {
          int cb2 = ks * 64 + (l >> 4) * 16;
          bf16x8 a = *reinterpret_cast<const bf16x8*>(
              xT + swz512(w * 16 + (l & 15), kh * 256 + cb2));
#pragma unroll
          for (int nf = 0; nf < 8; ++nf) {
            bf16x8 bb = *reinterpret_cast<const bf16x8*>(
                Wt + swz256(nf * 16 + (l & 15), cb2));
            acc[nf] = mfma16(a, bb, acc[nf]);
          }
        }
      } else {
#pragma unroll
        for (int ks = 0; ks < 4; ++ks) {
          int cb2 = ks * 64 + (l >> 4) * 16;
          bf16x8 a0 = *reinterpret_cast<const bf16x8*>(
              Wt + swz256(w * 32 + (l & 15), cb2));
          bf16x8 a1 = *reinterpret_cast<const bf16x8*>(
              Wt + swz256(w * 32 + 16 + (l & 15), cb2));
#pragma unroll
          for (int nf = 0; nf < 4; ++nf) {
            bf16x8 bb = *reinterpret_cast<const bf16x8*>(
                xT + swz512(nf * 16 + (l & 15), kh * 256 + cb2));
            acc[nf] = mfma16(a0, bb, acc[nf]);
            acc[4 + nf] = mfma16(a1, bb, acc[4 + nf]);
          }
        }
      }
    }

    if (p < 2) {
      bf16* dst = (p == 0) ? Qo : Ko;
#pragma unroll
      for (int nf = 0; nf < 8; ++nf) {
        float bias = bp[p][nf * 16 + (l & 15)];
#pragma unroll
        for (int r = 0; r < 4; ++r) {
          int n = n0 + w * 16 + (l >> 4) * 4 + r;
          int h = nf * 16 + (l & 15);
          dst[(size_t)(b * NDIM + n) * HDIM + h] = (bf16)(acc[nf][r] + bias);
        }
      }
    } else {
#pragma unroll
      for (int mf = 0; mf < 2; ++mf)
#pragma unroll
        for (int nf = 0; nf < 4; ++nf)
#pragma unroll
          for (int r = 0; r < 4; ++r) {
            int h = w * 32 + mf * 16 + (l >> 4) * 4 + r;
            int n = n0 + nf * 16 + (l & 15);
            Vo[(size_t)(b * HDIM + h) * NDIM + n] =
                (bf16)(acc[mf * 4 + nf][r] + bp[2][h]);
          }
    }
  }
}

// ---------------------------------------------------------------------------
// Kernel 2: flash attention. global_load_lds staging (counted vmcnt pipeline),
// swapped QK^T, in-register P, defer-max, split-k merge.
// grid 256 (XCD-swizzled), 512 threads = 8 waves = 4 q-subtiles x 2 k-halves.
// ---------------------------------------------------------------------------
__global__ __launch_bounds__(512, 2) void k2_attn(
    const bf16* __restrict__ Q, const bf16* __restrict__ K,
    const bf16* __restrict__ V, bf16* __restrict__ O) {
  extern __shared__ char lds[];
  // buf0 @0, buf1 @65536; each: Kt [128 kpos][256B] @0, Vt [128 d][256B] @32768

  const int t = threadIdx.x;
  const int l = t & 63;
  const int w = t >> 6;     // 0..7
  const int wm = w >> 1;    // q-subtile 0..3 (32 rows each)
  const int wk = w & 1;     // kpos half 0..1
  const int hi = l >> 5;
  const int c31 = l & 31;

  const int pid = blockIdx.x;
  const int b = (pid & 7) * 2 + ((pid >> 3) >> 4);
  const int q0 = ((pid >> 3) & 15) * 128;

  // Q fragments, B-operand layout: lane holds Q[q0+wm*32+c31][cs*16+hi*8+j]
  bf16x8 qf[8];
  {
    const bf16* qrow = Q + (size_t)(b * NDIM + q0 + wm * 32 + c31) * HDIM + hi * 8;
#pragma unroll
    for (int cs = 0; cs < 8; ++cs)
      qf[cs] = *reinterpret_cast<const bf16x8*>(qrow + cs * 16);
  }

  // Staging: waves 0-3 -> Kt rows w*32..; waves 4-7 -> Vt rows (w-4)*32..
  // LDS dest is linear (wave-uniform base + lane*16, matching global_load_lds);
  // the XOR swizzle is folded into the per-lane GLOBAL source address, so
  // LDS slot s of row r holds source chunk (s ^ (r&15)).  [rule #21]
  const bool isV = (w >= 4);
  const int wv = isV ? (w - 4) : w;
  const int slot = l & 15;
  const bf16* gbase[8];
#pragma unroll
  for (int i = 0; i < 8; ++i) {
    int r = wv * 32 + (l >> 4) + i * 4;
    int so = (slot ^ (r & 15)) * 8;
    gbase[i] = isV ? (V + (size_t)(b * HDIM + r) * NDIM + so)
                   : (K + (size_t)(b * NDIM + r) * HDIM + so);
  }
  const size_t gstep = isV ? (size_t)KVB : (size_t)KVB * HDIM;
  const int stagebase = (isV ? 32768 : 0) + wv * 8192;  // +i*1024; HW adds lane*16

  f32x16 oacc[4];
#pragma unroll
  for (int dg = 0; dg < 4; ++dg)
#pragma unroll
    for (int r = 0; r < 16; ++r) oacc[dg][r] = 0.f;
  float m_run = -1.0e30f, l_run = 0.f;

  // prologue: issue tile 0 loads
#pragma unroll
  for (int i = 0; i < 8; ++i)
    gload16(gbase[i], lds + stagebase + i * 1024);

#pragma unroll 1
  for (int kt = 0; kt < NT; ++kt) {
    char* buf = lds + (kt & 1) * 65536;
    if (kt + 1 < NT) {
      // issue next tile into the other buffer (free since end of iter kt-1)
      char* nbuf = lds + ((kt + 1) & 1) * 65536;
      const size_t off = (size_t)(kt + 1) * gstep;
#pragma unroll
      for (int i = 0; i < 8; ++i)
        gload16(gbase[i] + off, nbuf + stagebase + i * 1024);
      asm volatile("s_waitcnt vmcnt(8)" ::: "memory");  // tile kt landed
    } else {
      asm volatile("s_waitcnt vmcnt(0)" ::: "memory");
    }
    __builtin_amdgcn_s_barrier();

    const char* Kt = buf;
    const char* Vt = buf + 32768;
    const int rx = l & 15;  // row&15 for both kf and vf reads (rows = c31 mod 16)

    // S^T = mfma(K, Q): D[kpos_local][q], lane = q (col), kpos in regs.
    f32x16 s[2];
#pragma unroll
    for (int kg = 0; kg < 2; ++kg)
#pragma unroll
      for (int r = 0; r < 16; ++r) s[kg][r] = 0.f;
    __builtin_amdgcn_s_setprio(1);
#pragma unroll
    for (int kg = 0; kg < 2; ++kg) {
      const char* kr = Kt + (wk * 64 + kg * 32 + c31) * 256;
#pragma unroll
      for (int cs = 0; cs < 8; ++cs) {
        bf16x8 kf = *reinterpret_cast<const bf16x8*>(kr + (((cs * 2 + hi) ^ rx) * 16));
        s[kg] = mfma32(kf, qf[cs], s[kg]);
      }
    }
    __builtin_amdgcn_s_setprio(0);

    // Online softmax, lane-local (lane = q); hi/lo kpos halves combine via xor32.
    float mt = s[0][0];
#pragma unroll
    for (int r = 1; r < 16; ++r) mt = fmaxf(mt, s[0][r]);
#pragma unroll
    for (int r = 0; r < 16; ++r) mt = fmaxf(mt, s[1][r]);
    mt = fmaxf(mt, __shfl_xor(mt, 32));

    float fac = 1.0f;
    if (!__all(mt - m_run <= 8.0f)) {   // defer-max: rare rescale path
      float mnew = fmaxf(m_run, mt);
      fac = __builtin_amdgcn_exp2f((m_run - mnew) * LOG2E);
      m_run = mnew;
      int fbits = __builtin_bit_cast(int, fac);
#pragma unroll
      for (int r = 0; r < 16; ++r) {
        int srcl = ((r & 3) + 8 * (r >> 2) + 4 * hi) * 4;
        float fr = __builtin_bit_cast(
            float, __builtin_amdgcn_ds_bpermute(srcl, fbits));
#pragma unroll
        for (int dg = 0; dg < 4; ++dg) oacc[dg][r] *= fr;
      }
    }

    float sum = 0.f;
#pragma unroll
    for (int kg = 0; kg < 2; ++kg)
#pragma unroll
      for (int r = 0; r < 16; ++r) {
        float p = __builtin_amdgcn_exp2f((s[kg][r] - m_run) * LOG2E);
        s[kg][r] = p;
        sum += p;
      }
    sum += __shfl_xor(sum, 32);
    l_run = l_run * fac + sum;

    // P -> bf16 A-fragments in-register (cvt_pk + permlane32_swap), then PV.
    __builtin_amdgcn_s_setprio(1);
#pragma unroll
    for (int kg = 0; kg < 2; ++kg) {
      unsigned w0 = cvtpk(s[kg][0], s[kg][1]);
      unsigned w1 = cvtpk(s[kg][2], s[kg][3]);
      unsigned w2 = cvtpk(s[kg][4], s[kg][5]);
      unsigned w3 = cvtpk(s[kg][6], s[kg][7]);
      unsigned w4 = cvtpk(s[kg][8], s[kg][9]);
      unsigned w5 = cvtpk(s[kg][10], s[kg][11]);
      unsigned w6 = cvtpk(s[kg][12], s[kg][13]);
      unsigned w7 = cvtpk(s[kg][14], s[kg][15]);
      pswap(w0, w2); pswap(w1, w3); pswap(w4, w6); pswap(w5, w7);
      u32x4 pw0 = {w0, w1, w2, w3};
      u32x4 pw1 = {w4, w5, w6, w7};
      bf16x8 pa0 = __builtin_bit_cast(bf16x8, pw0);
      bf16x8 pa1 = __builtin_bit_cast(bf16x8, pw1);
#pragma unroll
      for (int dg = 0; dg < 4; ++dg) {
        const char* vr = Vt + (dg * 32 + c31) * 256;
        bf16x8 vf0 = *reinterpret_cast<const bf16x8*>(
            vr + (((wk * 8 + kg * 4 + 0 + hi) ^ rx) * 16));
        oacc[dg] = mfma32(pa0, vf0, oacc[dg]);
        bf16x8 vf1 = *reinterpret_cast<const bf16x8*>(
            vr + (((wk * 8 + kg * 4 + 2 + hi) ^ rx) * 16));
        oacc[dg] = mfma32(pa1, vf1, oacc[dg]);
      }
    }
    __builtin_amdgcn_s_setprio(0);
    __builtin_amdgcn_s_barrier();  // all waves done reading buf
  }

  // ---- split-k merge across (wk=0, wk=1) wave pairs; tile buffers are dead.
  float* O1 = (float*)lds;                  // 64 KB partials from wk==1
  float* M1 = (float*)(lds + 65536);        // [4][64]
  float* L1 = (float*)(lds + 66560);
  float* G0 = (float*)(lds + 67584);
  float* G1 = (float*)(lds + 68608);

  if (wk == 1) {
#pragma unroll
    for (int dg = 0; dg < 4; ++dg)
#pragma unroll
      for (int r = 0; r < 16; ++r)
        O1[(((wm * 4 + dg) * 16 + r) << 6) + l] = oacc[dg][r];
    M1[wm * 64 + l] = m_run;
    L1[wm * 64 + l] = l_run;
  }
  __syncthreads();
  if (wk == 0) {
    float m1 = M1[wm * 64 + l];
    float l1v = L1[wm * 64 + l];
    float mf = fmaxf(m_run, m1);
    float a0 = __builtin_amdgcn_exp2f((m_run - mf) * LOG2E);
    float a1 = __builtin_amdgcn_exp2f((m1 - mf) * LOG2E);
    float lf = l_run * a0 + l1v * a1;
    G0[wm * 64 + l] = a0 / lf;
    G1[wm * 64 + l] = a1 / lf;
    asm volatile("s_waitcnt lgkmcnt(0)" ::: "memory");
    f32x4 g0v[4], g1v[4];
#pragma unroll
    for (int gi = 0; gi < 4; ++gi) {
      int qi = wm * 64 + hi * 32 + gi * 8 + hi * 4;
      g0v[gi] = *reinterpret_cast<const f32x4*>(&G0[qi]);
      g1v[gi] = *reinterpret_cast<const f32x4*>(&G1[qi]);
    }
#pragma unroll
    for (int dg = 0; dg < 4; ++dg) {
      int h = dg * 32 + c31;
#pragma unroll
      for (int r = 0; r < 16; ++r) {
        float o1 = O1[(((wm * 4 + dg) * 16 + r) << 6) + l];
        float val = oacc[dg][r] * g0v[r >> 2][r & 3] + o1 * g1v[r >> 2][r & 3];
        int n = q0 + wm * 32 + (r & 3) + 8 * (r >> 2) + 4 * hi;
        O[(size_t)(b * NDIM + n) * HDIM + h] = (bf16)val;
      }
    }
  }
}

// ---------------------------------------------------------------------------
// Kernel 3: out = Wf @ O + bf + x (unchanged; near HBM roofline)
// ---------------------------------------------------------------------------
__global__ __launch_bounds__(256) void k3_proj(
    const bf16* __restrict__ O, const float* __restrict__ Wf,
    const float* __restrict__ bfv, const float* __restrict__ x,
    float* __restrict__ out) {
  __shared__ char lds[49152];
  char* Wt = lds;
  char* Ot = lds + 32768;

  const int t = threadIdx.x;
  const int l = t & 63;
  const int w = t >> 6;
  const int b = blockIdx.x >> 5;
  const int n0 = (blockIdx.x & 31) * 64;

#pragma unroll
  for (int pass = 0; pass < 4; ++pass) {
    int n = pass * 16 + (t >> 4);
    int hq = t & 15;
    uint4 d = *reinterpret_cast<const uint4*>(
        O + (size_t)(b * NDIM + n0 + n) * HDIM + hq * 8);
    *reinterpret_cast<uint4*>(Ot + swz256(n, hq * 16)) = d;
  }

#pragma unroll 1
  for (int ch = 0; ch < 2; ++ch) {
    __syncthreads();
#pragma unroll
    for (int pass = 0; pass < 8; ++pass) {
      int cl = pass * 16 + (t >> 4);
      int hq = t & 15;
      const float* src = Wf + (size_t)(ch * 128 + cl) * HDIM + hq * 8;
      float4 v0 = *reinterpret_cast<const float4*>(src);
      float4 v1 = *reinterpret_cast<const float4*>(src + 4);
      *reinterpret_cast<bf16x8*>(Wt + swz256(cl, hq * 16)) = cvt8(v0, v1);
    }
    __syncthreads();

    f32x4 acc[2][4];
#pragma unroll
    for (int i = 0; i < 2; ++i)
#pragma unroll
      for (int j = 0; j < 4; ++j) acc[i][j] = f32x4{0.f, 0.f, 0.f, 0.f};

#pragma unroll
    for (int ks = 0; ks < 4; ++ks) {
      int cb = ks * 64 + (l >> 4) * 16;
      bf16x8 a0 = *reinterpret_cast<const bf16x8*>(
          Wt + swz256(w * 32 + (l & 15), cb));
      bf16x8 a1 = *reinterpret_cast<const bf16x8*>(
          Wt + swz256(w * 32 + 16 + (l & 15), cb));
#pragma unroll
      for (int nf = 0; nf < 4; ++nf) {
        bf16x8 bb = *reinterpret_cast<const bf16x8*>(
            Ot + swz256(nf * 16 + (l & 15), cb));
        acc[0][nf] = mfma16(a0, bb, acc[0][nf]);
        acc[1][nf] = mfma16(a1, bb, acc[1][nf]);
      }
    }

#pragma unroll
    for (int mf = 0; mf < 2; ++mf)
#pragma unroll
      for (int nf = 0; nf < 4; ++nf)
#pragma unroll
        for (int r = 0; r < 4; ++r) {
          int c = ch * 128 + w * 32 + mf * 16 + (l >> 4) * 4 + r;
          int n = n0 + nf * 16 + (l & 15);
          size_t idx = (size_t)(b * CDIM + c) * NDIM + n;
          out[idx] = acc[mf][nf][r] + bfv[c] + x[idx];
        }
  }
}

extern "C" void kernel_launch(void* const* d_in, const int* in_sizes, int n_in,
                              void* d_out, int out_size, void* d_ws,
                              size_t ws_size, hipStream_t stream) {
  (void)in_sizes; (void)n_in; (void)out_size;
  const float* x = (const float*)d_in[0];
  const float* Wq = (const float*)d_in[1];
  const float* bq = (const float*)d_in[2];
  const float* Wk = (const float*)d_in[3];
  const float* bk = (const float*)d_in[4];
  const float* Wv = (const float*)d_in[5];
  const float* bv = (const float*)d_in[6];
  const float* Wf = (const float*)d_in[7];
  const float* bfv = (const float*)d_in[8];
  float* out = (float*)d_out;

  if (ws_size < (24u << 20)) return;
  char* ws = (char*)d_ws;
  bf16* Qb = (bf16*)(ws);                  // 8 MB [B][N][H]; reused as O
  bf16* Kb = (bf16*)(ws + (8u << 20));     // 8 MB [B][N][H]
  bf16* Vb = (bf16*)(ws + (16u << 20));    // 8 MB [B][H][N]

  const unsigned k2_lds = 131072;  // 2 x 64 KB double buffer (merge reuses it)
  hipFuncSetAttribute(reinterpret_cast<const void*>(k2_attn),
                      hipFuncAttributeMaxDynamicSharedMemorySize, (int)k2_lds);

  k1_qkv<<<512, 256, 0, stream>>>(x, Wq, bq, Wk, bk, Wv, bv, Qb, Kb, Vb);
  k2_attn<<<256, 512, k2_lds, stream>>>(Qb, Kb, Vb, Qb);
  k3_proj<<<512, 256, 0, stream>>>(Qb, Wf, bfv, x, out);
}